// Round 9
// baseline (247.326 us; speedup 1.0000x reference)
//
#include <hip/hip_runtime.h>
#include <hip/hip_bf16.h>

// ---------------------------------------------------------------------------
// SAGEModel fused pipeline (bf16 data path, fp32 accumulation):
//   hbf  = bf16(h)                              [100000,128]
//   y0   = segsum(hbf[src0])  -> bf16           [25000,128]
//   t    = relu(y0@W1+b1)@W2  -> bf16 (MFMA)    [25000,64]
//   out  = segsum(t[src1]) + b2 -> f32          [5000,64]
//
// R8 post-mortem: every scatter-based bucket fill is bound by sparse 4B
// writes to distinct 64B lines (40-62MB L2-boundary traffic for 2.9MB of
// payload), regardless of counter layout. This version is SCATTER-FREE:
// 150 blocks each own 200 dsts and scan the packed-ushort dst stream
// (broadcast L2 reads), staging matches in LDS, then write compact CSR
// lists coalesced. No global atomics, no memsets.
// ---------------------------------------------------------------------------

#define D0_CONST 25000
#define D1_CONST 5000
#define DPB 200                 // dsts per fill block
#define NFB0 125                // D0/DPB
#define NFB1 25                 // D1/DPB
#define NFB 150
#define SCAP 8192               // staged edges per block (mean 4800, 49 sigma)

typedef __attribute__((ext_vector_type(8))) short bf16x8;
typedef __attribute__((ext_vector_type(4))) float f32x4;
typedef __attribute__((ext_vector_type(4))) float f32x4v;
typedef __attribute__((ext_vector_type(4))) unsigned int u32x4;

__device__ __forceinline__ unsigned short f2bf(float f) {
    __hip_bfloat16 b = __float2bfloat16(f);
    return *(unsigned short*)&b;
}
// XOR swizzle within a 128-elem bf16 row (16B chunk keyed by row&7).
__device__ __forceinline__ int swzi(int row, int e) {
    return row * 128 + (e ^ ((row & 7) << 3));
}
// Accumulate 8 bf16 (packed uint4) into a[0..7] fp32.
__device__ __forceinline__ void acc8(float* a, uint4 v) {
    a[0] += __uint_as_float(v.x << 16);
    a[1] += __uint_as_float(v.x & 0xffff0000u);
    a[2] += __uint_as_float(v.y << 16);
    a[3] += __uint_as_float(v.y & 0xffff0000u);
    a[4] += __uint_as_float(v.z << 16);
    a[5] += __uint_as_float(v.z & 0xffff0000u);
    a[6] += __uint_as_float(v.w << 16);
    a[7] += __uint_as_float(v.w & 0xffff0000u);
}
__device__ __forceinline__ f32x4v ntload_f4(const float* p) {
    return __builtin_nontemporal_load((const f32x4v*)p);
}
__device__ __forceinline__ void ntstore_u4(unsigned int* p, u32x4 v) {
    __builtin_nontemporal_store(v, (u32x4*)p);
}

// --- prep: pack dst0/dst1 to ushort + W1,W2 -> transposed bf16 --------------
__global__ __launch_bounds__(256) void prep_pack(
    const int* __restrict__ dst0, const int* __restrict__ dst1,
    unsigned short* __restrict__ d0p, unsigned short* __restrict__ d1p,
    const float* __restrict__ W1, const float* __restrict__ W2,
    unsigned short* __restrict__ W1T, unsigned short* __restrict__ W2T,
    int n0, int n1)   // n0=E0/8, n1=E1/8
{
    int i = blockIdx.x * 256 + threadIdx.x;
    if (i < n0) {
        int4 a = ((const int4*)dst0)[i * 2];
        int4 b = ((const int4*)dst0)[i * 2 + 1];
        u32x4 o;
        o.x = (unsigned)a.x | ((unsigned)a.y << 16);
        o.y = (unsigned)a.z | ((unsigned)a.w << 16);
        o.z = (unsigned)b.x | ((unsigned)b.y << 16);
        o.w = (unsigned)b.z | ((unsigned)b.w << 16);
        ((u32x4*)d0p)[i] = o;
    } else if (i < n0 + n1) {
        int j = i - n0;
        int4 a = ((const int4*)dst1)[j * 2];
        int4 b = ((const int4*)dst1)[j * 2 + 1];
        u32x4 o;
        o.x = (unsigned)a.x | ((unsigned)a.y << 16);
        o.y = (unsigned)a.z | ((unsigned)a.w << 16);
        o.z = (unsigned)b.x | ((unsigned)b.y << 16);
        o.w = (unsigned)b.z | ((unsigned)b.w << 16);
        ((u32x4*)d1p)[j] = o;
    } else {
        int j = i - n0 - n1;
        if (j < 128 * 128) {
            int k = j >> 7, n = j & 127;
            W1T[n * 128 + k] = f2bf(W1[j]);
        } else {
            int j2 = j - 128 * 128;
            if (j2 < 128 * 64) {
                int k = j2 >> 6, n = j2 & 63;
                W2T[n * 128 + k] = f2bf(W2[j2]);
            }
        }
    }
}

// --- fused: scatter-free CSR fill (150 range-blocks) + nt h->bf16 cast ------
__global__ __launch_bounds__(256) void fill_cast_kernel(
    const unsigned short* __restrict__ d0p, const int* __restrict__ src0,
    const unsigned short* __restrict__ d1p, const int* __restrict__ src1,
    int E0, int E1,
    int* __restrict__ bkt0c, int* __restrict__ cnt0g, int* __restrict__ offs0g,
    int* __restrict__ bkt1c, int* __restrict__ cnt1g, int* __restrict__ offs1g,
    const float* __restrict__ hf, unsigned int* __restrict__ hbf, int n8)
{
    __shared__ int st[SCAP];        // (edge_idx<<8) | dst_local
    __shared__ int sc[256];         // counts -> inclusive scan
    __shared__ int cur[256];        // placement cursors
    __shared__ int scnt;

    int b = blockIdx.x;
    int t = threadIdx.x;

    if (b < NFB) {
        const unsigned short* dp; const int* sp;
        int E, dbase, gbase;
        int *bktc, *cntg, *offsg;
        if (b < NFB0) {
            dp = d0p; sp = src0; E = E0;
            dbase = b * DPB; gbase = b * SCAP;
            bktc = bkt0c; cntg = cnt0g; offsg = offs0g;
        } else {
            int bb = b - NFB0;
            dp = d1p; sp = src1; E = E1;
            dbase = bb * DPB; gbase = bb * SCAP;
            bktc = bkt1c; cntg = cnt1g; offsg = offs1g;
        }
        if (t == 0) scnt = 0;
        sc[t] = 0;
        __syncthreads();

        // Single scan of the packed dst stream; stage matches in LDS.
        int nv = E >> 3;                       // 16B vectors of 8 ushorts
        for (int v = t; v < nv; v += 256) {
            u32x4 pk = ((const u32x4*)dp)[v];
            unsigned w0 = pk.x, w1 = pk.y, w2 = pk.z, w3 = pk.w;
            unsigned ws[4] = {w0, w1, w2, w3};
            #pragma unroll
            for (int k = 0; k < 8; ++k) {
                int dv = (int)((ws[k >> 1] >> ((k & 1) * 16)) & 0xffffu);
                unsigned dl = (unsigned)(dv - dbase);
                if (dl < DPB) {
                    int p = atomicAdd(&scnt, 1);
                    if (p < SCAP) st[p] = ((v * 8 + k) << 8) | (int)dl;
                }
            }
        }
        __syncthreads();
        int s = scnt; if (s > SCAP) s = SCAP;

        // Count per dst_local.
        for (int i = t; i < s; i += 256) atomicAdd(&sc[st[i] & 255], 1);
        __syncthreads();
        int myc = sc[t];
        // Inclusive Hillis-Steele scan over 256 entries.
        for (int off = 1; off < 256; off <<= 1) {
            int v2 = (t >= off) ? sc[t - off] : 0;
            __syncthreads();
            sc[t] += v2;
            __syncthreads();
        }
        int excl = sc[t] - myc;
        if (t < DPB) {
            cntg[dbase + t]  = myc;
            offsg[dbase + t] = gbase + excl;
        }
        cur[t] = excl;
        __syncthreads();

        // Place: fetch src (independent loads, MLP), write compact lists.
        for (int i = t; i < s; i += 256) {
            int e  = st[i];
            int dl = e & 255;
            int sv = sp[e >> 8];
            int p  = atomicAdd(&cur[dl], 1);
            bktc[gbase + p] = sv;
        }
    } else {
        int i = (b - NFB) * 256 + t;
        if (i < n8) {
            f32x4v a = ntload_f4(hf + (size_t)i * 8);
            f32x4v c = ntload_f4(hf + (size_t)i * 8 + 4);
            u32x4 o;
            o.x = f2bf(a.x) | ((unsigned)f2bf(a.y) << 16);
            o.y = f2bf(a.z) | ((unsigned)f2bf(a.w) << 16);
            o.z = f2bf(c.x) | ((unsigned)f2bf(c.y) << 16);
            o.w = f2bf(c.z) | ((unsigned)f2bf(c.w) << 16);
            ntstore_u4(hbf + (size_t)i * 4, o);
        }
    }
}

// --- gather0: y0bf[d] = bf16( sum over CSR list d of hbf[s] ) ----------------
// 8 lanes/row, 32B/lane, 4-row unroll => 8 outstanding 16B loads/lane.
__global__ __launch_bounds__(256) void gather0_kernel(
    const uint4* __restrict__ x,       // [N0,16] uint4 view of bf16 [N0,128]
    const int* __restrict__ bktc,
    const int* __restrict__ cntg,
    const int* __restrict__ offsg,
    uint4* __restrict__ y,             // [D0,16]
    int D)
{
    int tid = blockIdx.x * 256 + threadIdx.x;
    int d = tid >> 3;
    int c = tid & 7;
    if (d >= D) return;
    int n = cntg[d];
    int base = offsg[d];

    float a[16];
    #pragma unroll
    for (int q = 0; q < 16; ++q) a[q] = 0.f;

    int i = 0;
    for (; i + 4 <= n; i += 4) {
        int s0 = bktc[base + i];
        int s1 = bktc[base + i + 1];
        int s2 = bktc[base + i + 2];
        int s3 = bktc[base + i + 3];
        uint4 v0a = x[(size_t)s0 * 16 + c * 2];
        uint4 v0b = x[(size_t)s0 * 16 + c * 2 + 1];
        uint4 v1a = x[(size_t)s1 * 16 + c * 2];
        uint4 v1b = x[(size_t)s1 * 16 + c * 2 + 1];
        uint4 v2a = x[(size_t)s2 * 16 + c * 2];
        uint4 v2b = x[(size_t)s2 * 16 + c * 2 + 1];
        uint4 v3a = x[(size_t)s3 * 16 + c * 2];
        uint4 v3b = x[(size_t)s3 * 16 + c * 2 + 1];
        acc8(a, v0a); acc8(a + 8, v0b);
        acc8(a, v1a); acc8(a + 8, v1b);
        acc8(a, v2a); acc8(a + 8, v2b);
        acc8(a, v3a); acc8(a + 8, v3b);
    }
    for (; i < n; ++i) {
        int s0 = bktc[base + i];
        acc8(a,     x[(size_t)s0 * 16 + c * 2]);
        acc8(a + 8, x[(size_t)s0 * 16 + c * 2 + 1]);
    }

    uint4 o0, o1;
    o0.x = f2bf(a[0])  | ((unsigned)f2bf(a[1])  << 16);
    o0.y = f2bf(a[2])  | ((unsigned)f2bf(a[3])  << 16);
    o0.z = f2bf(a[4])  | ((unsigned)f2bf(a[5])  << 16);
    o0.w = f2bf(a[6])  | ((unsigned)f2bf(a[7])  << 16);
    o1.x = f2bf(a[8])  | ((unsigned)f2bf(a[9])  << 16);
    o1.y = f2bf(a[10]) | ((unsigned)f2bf(a[11]) << 16);
    o1.z = f2bf(a[12]) | ((unsigned)f2bf(a[13]) << 16);
    o1.w = f2bf(a[14]) | ((unsigned)f2bf(a[15]) << 16);
    y[(size_t)d * 16 + c * 2]     = o0;
    y[(size_t)d * 16 + c * 2 + 1] = o1;
}

// --- fused linear: t = bf16( relu(y0@W1 + b1) @ W2 ) via MFMA ---------------
__global__ __launch_bounds__(256) void fused_linear(
    const unsigned short* __restrict__ y0bf,   // [M,128]
    const unsigned short* __restrict__ W1T,    // [128n][128k]
    const unsigned short* __restrict__ W2T,    // [64n][128k]
    const float* __restrict__ b1,              // [128]
    unsigned short* __restrict__ t,            // [M,64]
    int M)
{
    __shared__ unsigned short Ys[128 * 128];
    __shared__ unsigned short W1s[128 * 128];
    __shared__ unsigned short W2s[64 * 128];

    int tid = threadIdx.x;
    int r0 = blockIdx.x * 128;

    for (int idx = tid; idx < 2048; idx += 256) {
        int r = idx >> 4, ch = idx & 15;
        uint4 v = make_uint4(0, 0, 0, 0);
        if (r0 + r < M) v = *(const uint4*)&y0bf[(size_t)(r0 + r) * 128 + ch * 8];
        *(uint4*)&Ys[swzi(r, ch * 8)] = v;
    }
    for (int idx = tid; idx < 2048; idx += 256) {
        int r = idx >> 4, ch = idx & 15;
        *(uint4*)&W1s[swzi(r, ch * 8)] = *(const uint4*)&W1T[r * 128 + ch * 8];
    }
    for (int idx = tid; idx < 1024; idx += 256) {
        int r = idx >> 4, ch = idx & 15;
        *(uint4*)&W2s[swzi(r, ch * 8)] = *(const uint4*)&W2T[r * 128 + ch * 8];
    }
    __syncthreads();

    int w = tid >> 6, lane = tid & 63;
    int lr = lane & 15, lhi = lane >> 4;
    int wr = 32 * w;

    bf16x8 a[2][4];
    #pragma unroll
    for (int m = 0; m < 2; ++m)
        #pragma unroll
        for (int kt = 0; kt < 4; ++kt)
            a[m][kt] = *(bf16x8*)&Ys[swzi(wr + 16 * m + lr, kt * 32 + lhi * 8)];

    f32x4 acc1[2][8];
    #pragma unroll
    for (int m = 0; m < 2; ++m)
        #pragma unroll
        for (int ct = 0; ct < 8; ++ct) acc1[m][ct] = (f32x4)(0.f);

    #pragma unroll
    for (int ct = 0; ct < 8; ++ct) {
        #pragma unroll
        for (int kt = 0; kt < 4; ++kt) {
            bf16x8 b = *(bf16x8*)&W1s[swzi(ct * 16 + lr, kt * 32 + lhi * 8)];
            acc1[0][ct] = __builtin_amdgcn_mfma_f32_16x16x32_bf16(a[0][kt], b, acc1[0][ct], 0, 0, 0);
            acc1[1][ct] = __builtin_amdgcn_mfma_f32_16x16x32_bf16(a[1][kt], b, acc1[1][ct], 0, 0, 0);
        }
    }

    #pragma unroll
    for (int ct = 0; ct < 8; ++ct) {
        float bv = b1[ct * 16 + lr];
        #pragma unroll
        for (int m = 0; m < 2; ++m)
            #pragma unroll
            for (int q = 0; q < 4; ++q) {
                float v = fmaxf(acc1[m][ct][q] + bv, 0.f);
                Ys[swzi(wr + 16 * m + lhi * 4 + q, ct * 16 + lr)] = f2bf(v);
            }
    }

    bf16x8 a2[2][4];
    #pragma unroll
    for (int m = 0; m < 2; ++m)
        #pragma unroll
        for (int kt = 0; kt < 4; ++kt)
            a2[m][kt] = *(bf16x8*)&Ys[swzi(wr + 16 * m + lr, kt * 32 + lhi * 8)];

    f32x4 acc2[2][4];
    #pragma unroll
    for (int m = 0; m < 2; ++m)
        #pragma unroll
        for (int ct = 0; ct < 4; ++ct) acc2[m][ct] = (f32x4)(0.f);

    #pragma unroll
    for (int ct = 0; ct < 4; ++ct) {
        #pragma unroll
        for (int kt = 0; kt < 4; ++kt) {
            bf16x8 b = *(bf16x8*)&W2s[swzi(ct * 16 + lr, kt * 32 + lhi * 8)];
            acc2[0][ct] = __builtin_amdgcn_mfma_f32_16x16x32_bf16(a2[0][kt], b, acc2[0][ct], 0, 0, 0);
            acc2[1][ct] = __builtin_amdgcn_mfma_f32_16x16x32_bf16(a2[1][kt], b, acc2[1][ct], 0, 0, 0);
        }
    }

    #pragma unroll
    for (int m = 0; m < 2; ++m)
        #pragma unroll
        for (int ct = 0; ct < 4; ++ct)
            #pragma unroll
            for (int q = 0; q < 4; ++q) {
                int row = r0 + wr + 16 * m + lhi * 4 + q;
                if (row < M) t[(size_t)row * 64 + ct * 16 + lr] = f2bf(acc2[m][ct][q]);
            }
}

// --- gather1: out[d] = sum over CSR list d of t[s], + b2, f32 out ------------
// 8 lanes/row, 16B/lane, 4-row unroll.
__global__ __launch_bounds__(256) void gather1_kernel(
    const uint4* __restrict__ x,       // [M,8] uint4 view of bf16 [M,64]
    const int* __restrict__ bktc,
    const int* __restrict__ cntg,
    const int* __restrict__ offsg,
    const float* __restrict__ b2,
    float4* __restrict__ out,          // [D1,16]
    int D)
{
    int tid = blockIdx.x * 256 + threadIdx.x;
    int d = tid >> 3;
    int c = tid & 7;
    if (d >= D) return;
    int n = cntg[d];
    int base = offsg[d];

    float a[8] = {0.f, 0.f, 0.f, 0.f, 0.f, 0.f, 0.f, 0.f};
    int i = 0;
    for (; i + 4 <= n; i += 4) {
        int s0 = bktc[base + i];
        int s1 = bktc[base + i + 1];
        int s2 = bktc[base + i + 2];
        int s3 = bktc[base + i + 3];
        uint4 v0 = x[(size_t)s0 * 8 + c];
        uint4 v1 = x[(size_t)s1 * 8 + c];
        uint4 v2 = x[(size_t)s2 * 8 + c];
        uint4 v3 = x[(size_t)s3 * 8 + c];
        acc8(a, v0); acc8(a, v1); acc8(a, v2); acc8(a, v3);
    }
    for (; i < n; ++i) acc8(a, x[(size_t)bktc[base + i] * 8 + c]);

    float4 blo = *(const float4*)&b2[c * 8];
    float4 bhi = *(const float4*)&b2[c * 8 + 4];
    float4 o0 = make_float4(a[0] + blo.x, a[1] + blo.y, a[2] + blo.z, a[3] + blo.w);
    float4 o1 = make_float4(a[4] + bhi.x, a[5] + bhi.y, a[6] + bhi.z, a[7] + bhi.w);
    out[(size_t)d * 16 + c * 2]     = o0;
    out[(size_t)d * 16 + c * 2 + 1] = o1;
}

extern "C" void kernel_launch(void* const* d_in, const int* in_sizes, int n_in,
                              void* d_out, int out_size, void* d_ws, size_t ws_size,
                              hipStream_t stream) {
    const float* h    = (const float*)d_in[0];
    const float* W1   = (const float*)d_in[1];
    const float* b1   = (const float*)d_in[2];
    const float* W2   = (const float*)d_in[3];
    const float* b2   = (const float*)d_in[4];
    const int*   src0 = (const int*)d_in[5];
    const int*   dst0 = (const int*)d_in[6];
    const int*   src1 = (const int*)d_in[7];
    const int*   dst1 = (const int*)d_in[8];

    const int N0 = in_sizes[0] / 128;    // 100000
    const int E0 = in_sizes[5];          // 600000 (multiple of 8)
    const int E1 = in_sizes[7];          // 120000 (multiple of 8)
    const int D0 = D0_CONST;
    const int D1 = D1_CONST;

    // Workspace layout (~42 MB), all 16B-aligned sizes.
    char* p = (char*)d_ws;
    unsigned short* hbf  = (unsigned short*)p; p += (size_t)N0 * 128 * 2;   // 25.6 MB
    unsigned short* y0bf = (unsigned short*)p; p += (size_t)D0 * 128 * 2;   // 6.4 MB
    unsigned short* tbf  = (unsigned short*)p; p += (size_t)D0 * 64 * 2;    // 3.2 MB
    unsigned short* W1T  = (unsigned short*)p; p += 128 * 128 * 2;
    unsigned short* W2T  = (unsigned short*)p; p += 64 * 128 * 2;
    unsigned short* d0p  = (unsigned short*)p; p += (size_t)E0 * 2;         // 1.2 MB
    unsigned short* d1p  = (unsigned short*)p; p += (size_t)E1 * 2;         // 0.24 MB
    int* bkt0c  = (int*)p; p += (size_t)NFB0 * SCAP * 4;                    // 4.0 MB
    int* bkt1c  = (int*)p; p += (size_t)NFB1 * SCAP * 4;                    // 0.8 MB
    int* cnt0g  = (int*)p; p += (size_t)D0 * 4;
    int* offs0g = (int*)p; p += (size_t)D0 * 4;
    int* cnt1g  = (int*)p; p += (size_t)D1 * 4;
    int* offs1g = (int*)p; p += (size_t)D1 * 4;

    float* out = (float*)d_out;

    // 1) pack dst streams to ushort + W transpose/cast (no memsets needed).
    {
        int n0 = E0 / 8, n1 = E1 / 8;
        int tot = n0 + n1 + 128 * 128 + 128 * 64;
        prep_pack<<<(tot + 255) / 256, 256, 0, stream>>>(
            dst0, dst1, d0p, d1p, W1, W2, W1T, W2T, n0, n1);
    }

    // 2) scatter-free CSR fill (150 blocks) + nt h->bf16 cast (co-scheduled).
    {
        int n8 = N0 * 128 / 8;                       // 1.6M
        int castBlocks = (n8 + 255) / 256;
        fill_cast_kernel<<<NFB + castBlocks, 256, 0, stream>>>(
            d0p, src0, d1p, src1, E0, E1,
            bkt0c, cnt0g, offs0g, bkt1c, cnt1g, offs1g,
            h, (unsigned int*)hbf, n8);
    }

    // 3) layer-0 aggregation.
    {
        long long threads = (long long)D0 * 8;
        gather0_kernel<<<(int)((threads + 255) / 256), 256, 0, stream>>>(
            (const uint4*)hbf, bkt0c, cnt0g, offs0g, (uint4*)y0bf, D0);
    }
    // 4) t = relu(y0@W1+b1)@W2
    fused_linear<<<(D0 + 127) / 128, 256, 0, stream>>>(y0bf, W1T, W2T, b1, tbf, D0);

    // 5) layer-1 aggregation + bias -> final output.
    {
        long long threads = (long long)D1 * 8;
        gather1_kernel<<<(int)((threads + 255) / 256), 256, 0, stream>>>(
            (const uint4*)tbf, bkt1c, cnt1g, offs1g, b2, (float4*)out, D1);
    }
}